// Round 18
// baseline (94.666 us; speedup 1.0000x reference)
//
#include <hip/hip_runtime.h>

// ---------------------------------------------------------------------------
// SwitchGLU MoE, round 18: stage1 counted-ring-3 AT 3 blocks/CU.
// Rate model (R12-R17): blocks/CU gates staging rate; counted-vs-drain only
// pays at 3/CU (stage2: ~10-11 TB/s counted@3/CU; stage1 drain@3/CU: 6.1).
// Ring-3 made to fit 48KB by BN=32-dual (wave = 64M x 16N of G and U):
// per-buf = X 8KB + G 4KB + U 4KB = 16KB; vmcnt(4), 2-step lookahead --
// the exact schedule shape proven in stage2. Staged bytes rise 330->400MB
// (X-dup x64 strips); breakeven rate 7.4 TB/s.
// Stage2 / cvtx / dispatch byte-identical to R17 (one variable).
// ---------------------------------------------------------------------------

typedef unsigned short u16;
typedef unsigned int   u32;
typedef u16    u16x8 __attribute__((ext_vector_type(8)));
typedef __bf16 bf16x8 __attribute__((ext_vector_type(8)));
typedef float  f32x4 __attribute__((ext_vector_type(4)));

#define NE   8
#define DDIM 768
#define HDIM 2048
#define NTOT 2048
#define NTOK 1024
#define MAXT2 24   // 128-row tiles

__device__ __forceinline__ u16 f2bf(float f) {
  return (u16)((__builtin_bit_cast(u32, f) + 0x8000u) >> 16);
}
__device__ __forceinline__ bf16x8 cvt8(float4 a, float4 b) {
  bf16x8 r;
  r[0] = (__bf16)a.x; r[1] = (__bf16)a.y; r[2] = (__bf16)a.z; r[3] = (__bf16)a.w;
  r[4] = (__bf16)b.x; r[5] = (__bf16)b.y; r[6] = (__bf16)b.z; r[7] = (__bf16)b.w;
  return r;
}
__device__ __forceinline__ f32x4 mfma(bf16x8 a, bf16x8 b, f32x4 c) {
  return __builtin_amdgcn_mfma_f32_16x16x32_bf16(a, b, c, 0, 0, 0);
}
__device__ __forceinline__ void gl16(const void* g, void* l) {
  __builtin_amdgcn_global_load_lds(
      (const __attribute__((address_space(1))) void*)g,
      (__attribute__((address_space(3))) void*)l, 16, 0, 0);
}
#define SCHEDB() __builtin_amdgcn_sched_barrier(0)
#define BAR()    __builtin_amdgcn_s_barrier()
#define VMW(n)   asm volatile("s_waitcnt vmcnt(" #n ")" ::: "memory")

// fp32 tile frag read (R5-verified pair): rows of 32 floats, 16B chunk ^= r&7
#define RD8(arr, o_, r_, kb_) cvt8(                                              \
    *(const float4*)&(arr)[(o_) + (r_) * 32 + ((((kb_)*2    ) ^ ((r_)&7)) << 2)], \
    *(const float4*)&(arr)[(o_) + (r_) * 32 + ((((kb_)*2 + 1) ^ ((r_)&7)) << 2)])
// bf16 tile frag read (R5-verified pair): rows of 32 u16, 16B chunk ^= (r>>1)&3
#define RDB(arr, o_, r_, kb_) __builtin_bit_cast(bf16x8,                         \
    *(const u16x8*)&(arr)[(o_) + (r_) * 32 + (((kb_) ^ (((r_)>>1)&3)) << 3)])

// ---------------------------------------------------------------------------
__global__ __launch_bounds__(256) void moe_cvtx(const float* __restrict__ x,
                                                u16* __restrict__ xb) {
  const int i = (blockIdx.x * 256 + threadIdx.x) * 8;
  const float4 f0 = *(const float4*)(x + i);
  const float4 f1 = *(const float4*)(x + i + 4);
  *(uint4*)(xb + i) = __builtin_bit_cast(uint4, cvt8(f0, f1));
}

// ---------------------------------------------------------------------------
// Dispatch: expert bucketing + 128-row tile table.
// meta: [0..8] offs, [14] ntiles128, [48+t] e128, [80+t] r0_128 (t<24).
// ---------------------------------------------------------------------------
__global__ void moe_dispatch(const int* __restrict__ idx,
                             int* __restrict__ meta, int* __restrict__ perm) {
  __shared__ int s_cnt[NE];
  __shared__ int s_off[NE + 1];
  __shared__ int s_cur[NE];
  const int tid = threadIdx.x;
  if (tid < NE) { s_cnt[tid] = 0; s_cur[tid] = 0; }
  __syncthreads();
  for (int n = tid; n < NTOT; n += 256) atomicAdd(&s_cnt[idx[n]], 1);
  __syncthreads();
  if (tid == 0) {
    int a = 0;
    for (int e = 0; e < NE; ++e) { s_off[e] = a; a += s_cnt[e]; }
    s_off[NE] = a;
  }
  __syncthreads();
  for (int n = tid; n < NTOT; n += 256) {
    const int e = idx[n];
    perm[s_off[e] + atomicAdd(&s_cur[e], 1)] = n;
  }
  if (tid == 0) {
    int t2 = 0;
    for (int e = 0; e < NE; ++e) {
      for (int r0 = s_off[e]; r0 < s_off[e + 1]; r0 += 128) {
        meta[48 + t2] = e; meta[80 + t2] = r0; ++t2;
      }
    }
    meta[14] = t2;
  }
  if (tid < NE + 1) meta[tid] = s_off[tid];
}

// ---------------------------------------------------------------------------
// Stage 1: h = silu(X Wg^T) * (X Wu^T).  BM=128, BN=32(G)+32(U), BK=32.
// grid = MAXT2*64 (tile t, H-strip nt of 32). 256 thr = 4 waves (2M x 2N);
// wave = 64M x 16N of both G and U. Ring-3 LDS 48KB -> 3 blocks/CU.
// 4 gl16/thread/step, counted vmcnt(4), 2-step lookahead (R13-s2 schedule).
// ---------------------------------------------------------------------------
__global__ __launch_bounds__(256, 3) void moe_stage1(
    const u16* __restrict__ xb, const int* __restrict__ perm,
    const int* __restrict__ meta, const float* __restrict__ wg,
    const float* __restrict__ wu, u16* __restrict__ hbuf) {
  const int t = blockIdx.x >> 6;
  if (t >= meta[14]) return;
  const int nt = blockIdx.x & 63;  // H cols nt*32
  const int e = meta[48 + t];
  const int r0 = meta[80 + t];
  const int rows = min(128, meta[e + 1] - r0);

  __shared__ __align__(16) u16   sX[3 * 128 * 32];  // 8KB/buf
  __shared__ __align__(16) float sG[3 * 32 * 32];   // 4KB/buf
  __shared__ __align__(16) float sU[3 * 32 * 32];   // 4KB/buf

  const int tid = threadIdx.x;
  const int lane = tid & 63;
  const int wv = tid >> 6;
  const int wm = (wv >> 1) * 64;   // 0,64
  const int wn = (wv & 1) * 16;    // 0,16
  const int fr = lane & 15, kb = lane >> 4;

  // X staging (bf16): 2 gl16/thread; row r, chunk (lane&3)^((r>>1)&3)
  const u16* gpX[2];
  int lbX[2];
#pragma unroll
  for (int j = 0; j < 2; ++j) {
    const int r = wv * 32 + j * 16 + (lane >> 2);
    const int tok = perm[r0 + min(r, rows - 1)] >> 1;  // TOPK=2
    gpX[j] = xb + (size_t)tok * DDIM + (((lane & 3) ^ ((r >> 1) & 3)) << 3);
    lbX[j] = (wv * 32 + j * 16) * 32;  // u16 units
  }
  // W staging (fp32, 32 rows): 1 gl16/thread each; row tid>>3, chunk
  // (tid&7)^(row&7). Wave wv covers rows wv*8..wv*8+7 (1KB) linearly.
  const int wr = tid >> 3;  // 0..31
  const float* gpG =
      wg + ((size_t)e * HDIM + nt * 32 + wr) * DDIM + (((tid & 7) ^ (wr & 7)) << 2);
  const float* gpU =
      wu + ((size_t)e * HDIM + nt * 32 + wr) * DDIM + (((tid & 7) ^ (wr & 7)) << 2);
  const int lbW = wv * 256;  // float units (1KB per wave)

  f32x4 aG[4] = {};
  f32x4 aU[4] = {};

#define S1_STAGE(slot, kt) do {                                   \
    const int ko_ = (kt) * 32;                                    \
    gl16(gpX[0] + ko_, &sX[(slot) * 4096 + lbX[0]]);              \
    gl16(gpX[1] + ko_, &sX[(slot) * 4096 + lbX[1]]);              \
    gl16(gpG + ko_, &sG[(slot) * 1024 + lbW]);                    \
    gl16(gpU + ko_, &sU[(slot) * 1024 + lbW]);                    \
  } while (0)

#define S1_COMPUTE(slot) do {                                     \
    const int su_ = (slot) * 4096, sf_ = (slot) * 1024;           \
    bf16x8 a0 = RDB(sX, su_, wm + fr, kb);                        \
    bf16x8 a1 = RDB(sX, su_, wm + 16 + fr, kb);                   \
    bf16x8 a2 = RDB(sX, su_, wm + 32 + fr, kb);                   \
    bf16x8 a3 = RDB(sX, su_, wm + 48 + fr, kb);                   \
    bf16x8 g0 = RD8(sG, sf_, wn + fr, kb);                        \
    bf16x8 u0 = RD8(sU, sf_, wn + fr, kb);                        \
    aG[0] = mfma(a0, g0, aG[0]);                                  \
    aG[1] = mfma(a1, g0, aG[1]);                                  \
    aG[2] = mfma(a2, g0, aG[2]);                                  \
    aG[3] = mfma(a3, g0, aG[3]);                                  \
    aU[0] = mfma(a0, u0, aU[0]);                                  \
    aU[1] = mfma(a1, u0, aU[1]);                                  \
    aU[2] = mfma(a2, u0, aU[2]);                                  \
    aU[3] = mfma(a3, u0, aU[3]);                                  \
  } while (0)

  S1_STAGE(0, 0);
  S1_STAGE(1, 1);
  VMW(4);   // buf0 complete; buf1's 4 still in flight
  BAR();

#pragma unroll 1
  for (int l = 0; l < 24; ++l) {
    if (l + 2 < 24) S1_STAGE((l + 2) % 3, l + 2);
    SCHEDB();
    S1_COMPUTE(l % 3);
    SCHEDB();
    if (l + 2 < 24) { VMW(4); BAR(); }
    else if (l == 22) { VMW(0); BAR(); }
  }

  // epilogue: C/D layout col=lane&15, row=(lane>>4)*4+reg
  const int crow = kb * 4, ccol = fr;
#pragma unroll
  for (int mi = 0; mi < 4; ++mi) {
#pragma unroll
    for (int ri = 0; ri < 4; ++ri) {
      const int lm = wm + mi * 16 + crow + ri;
      if (lm < rows) {
        u16* hb = hbuf + (size_t)(r0 + lm) * HDIM + nt * 32 + wn;
        const float gv = aG[mi][ri];
        const float uv = aU[mi][ri];
        const float h = gv / (1.0f + __expf(-gv)) * uv;
        hb[ccol] = f2bf(h);
      }
    }
  }
}

// ---------------------------------------------------------------------------
// Stage 2 (byte-identical to R13/R17): out += h Wd^T. BM=128/BN=64/BK=32,
// split-K=2. Ring-3 LDS 48KB (3 blocks/CU), counted vmcnt(4).
// ---------------------------------------------------------------------------
__global__ __launch_bounds__(256, 3) void moe_stage2(
    const u16* __restrict__ hbuf, const int* __restrict__ perm,
    const int* __restrict__ meta, const float* __restrict__ wd,
    float* __restrict__ out) {
  const int t = blockIdx.x / 24;
  if (t >= meta[14]) return;
  const int rem = blockIdx.x - t * 24;
  const int ks = rem / 12;
  const int nt = rem - ks * 12;
  const int e = meta[48 + t];
  const int r0 = meta[80 + t];
  const int rows = min(128, meta[e + 1] - r0);

  __shared__ __align__(16) u16   sA[3 * 128 * 32];
  __shared__ __align__(16) float sB[3 * 64 * 32];

  const int tid = threadIdx.x;
  const int lane = tid & 63;
  const int wv = tid >> 6;
  const int wm = (wv >> 1) * 64;
  const int wn = (wv & 1) * 32;

  const u16* gpA[2];
  int lbA[2];
#pragma unroll
  for (int j = 0; j < 2; ++j) {
    const int r = wv * 32 + j * 16 + (lane >> 2);
    gpA[j] = hbuf + (size_t)(r0 + min(r, rows - 1)) * HDIM + ks * 1024 +
             (((lane & 3) ^ ((r >> 1) & 3)) << 3);
    lbA[j] = (wv * 32 + j * 16) * 32;
  }
  const float* gpB[2];
  int lbB[2];
#pragma unroll
  for (int j = 0; j < 2; ++j) {
    const int r = wv * 16 + j * 8 + (lane >> 3);
    gpB[j] = wd + ((size_t)e * DDIM + nt * 64 + r) * HDIM + ks * 1024 +
             (((lane & 7) ^ (r & 7)) << 2);
    lbB[j] = (wv * 16 + j * 8) * 32;
  }

  f32x4 acc[4][2] = {};

#define S2_STAGE(slot, kp) do {                                   \
    const int su_ = (slot) * 4096, sf_ = (slot) * 2048;           \
    const int ko_ = (kp) * 32;                                    \
    gl16(gpA[0] + ko_, &sA[su_ + lbA[0]]);                        \
    gl16(gpA[1] + ko_, &sA[su_ + lbA[1]]);                        \
    gl16(gpB[0] + ko_, &sB[sf_ + lbB[0]]);                        \
    gl16(gpB[1] + ko_, &sB[sf_ + lbB[1]]);                        \
  } while (0)

#define S2_COMPUTE(slot) do {                                     \
    const int su_ = (slot) * 4096, sf_ = (slot) * 2048;           \
    const int fr_ = lane & 15, kb_ = lane >> 4;                   \
    bf16x8 a0 = RDB(sA, su_, wm + fr_, kb_);                      \
    bf16x8 a1 = RDB(sA, su_, wm + 16 + fr_, kb_);                 \
    bf16x8 a2 = RDB(sA, su_, wm + 32 + fr_, kb_);                 \
    bf16x8 a3 = RDB(sA, su_, wm + 48 + fr_, kb_);                 \
    bf16x8 b0 = RD8(sB, sf_, wn + fr_, kb_);                      \
    bf16x8 b1 = RD8(sB, sf_, wn + 16 + fr_, kb_);                 \
    acc[0][0] = mfma(a0, b0, acc[0][0]);                          \
    acc[1][0] = mfma(a1, b0, acc[1][0]);                          \
    acc[2][0] = mfma(a2, b0, acc[2][0]);                          \
    acc[3][0] = mfma(a3, b0, acc[3][0]);                          \
    acc[0][1] = mfma(a0, b1, acc[0][1]);                          \
    acc[1][1] = mfma(a1, b1, acc[1][1]);                          \
    acc[2][1] = mfma(a2, b1, acc[2][1]);                          \
    acc[3][1] = mfma(a3, b1, acc[3][1]);                          \
  } while (0)

  S2_STAGE(0, 0);
  S2_STAGE(1, 1);
  VMW(4);
  BAR();

#pragma unroll 1
  for (int l = 0; l < 32; ++l) {
    if (l + 2 < 32) S2_STAGE((l + 2) % 3, l + 2);
    SCHEDB();
    S2_COMPUTE(l % 3);
    SCHEDB();
    if (l + 2 < 32) { VMW(4); BAR(); }
    else if (l == 30) { VMW(0); BAR(); }
  }

  const int crow = (lane >> 4) << 2;
  const int ccol = lane & 15;
#pragma unroll
  for (int mi = 0; mi < 4; ++mi) {
#pragma unroll
    for (int ri = 0; ri < 4; ++ri) {
      const int lm = wm + mi * 16 + crow + ri;
      if (lm < rows) {
        const int tok = perm[r0 + lm];
        float* orow = out + (size_t)tok * DDIM + nt * 64 + wn;
#pragma unroll
        for (int nj = 0; nj < 2; ++nj) {
          atomicAdd(&orow[nj * 16 + ccol], acc[mi][nj][ri]);
        }
      }
    }
  }
}

// ---------------------------------------------------------------------------
extern "C" void kernel_launch(void* const* d_in, const int* in_sizes, int n_in,
                              void* d_out, int out_size, void* d_ws, size_t ws_size,
                              hipStream_t stream) {
  const float* x  = (const float*)d_in[0];
  const int* idx  = (const int*)d_in[1];
  const float* wg = (const float*)d_in[2];
  const float* wu = (const float*)d_in[3];
  const float* wd = (const float*)d_in[4];
  float* out = (float*)d_out;

  int* iws = (int*)d_ws;
  int* meta = iws;        // layout in moe_dispatch comment
  int* perm = iws + 128;  // 2048 ints
  u16* xbuf = (u16*)((char*)d_ws + 16384);              // 1024x768 bf16
  u16* hbuf = (u16*)((char*)d_ws + 16384 + (1 << 21));  // 2048x2048 bf16

  hipMemsetAsync(d_out, 0, (size_t)out_size * sizeof(float), stream);
  moe_cvtx<<<NTOK * DDIM / 2048, 256, 0, stream>>>(x, xbuf);
  moe_dispatch<<<1, 256, 0, stream>>>(idx, meta, perm);
  moe_stage1<<<MAXT2 * 64, 256, 0, stream>>>(xbuf, perm, meta, wg, wu, hbuf);
  moe_stage2<<<MAXT2 * 24, 256, 0, stream>>>(hbuf, perm, meta, wd, out);
}

// Round 19
// 82.331 us; speedup vs baseline: 1.1498x; 1.1498x over previous
//
#include <hip/hip_runtime.h>

// ---------------------------------------------------------------------------
// SwitchGLU MoE, round 19: stage1 = R17-exact (best known, 54.5us).
// Stage2 -> ring-2 (32KB LDS, 5 blocks/CU) counted-1-deep, 2 barriers/step:
//   compute(cur); lgkm(0); BAR;          // all waves done reading cur
//   stage(cur, l+2); VMW(4); BAR;        // (l+1) complete, (l+2) in flight
// Tests the last untested occupancy cell (>3 blocks/CU) on the fast kernel.
// ---------------------------------------------------------------------------

typedef unsigned short u16;
typedef unsigned int   u32;
typedef u16    u16x8 __attribute__((ext_vector_type(8)));
typedef __bf16 bf16x8 __attribute__((ext_vector_type(8)));
typedef float  f32x4 __attribute__((ext_vector_type(4)));

#define NE   8
#define DDIM 768
#define HDIM 2048
#define NTOT 2048
#define NTOK 1024
#define MAXT2 24   // 128-row tiles

__device__ __forceinline__ u16 f2bf(float f) {
  return (u16)((__builtin_bit_cast(u32, f) + 0x8000u) >> 16);
}
__device__ __forceinline__ bf16x8 cvt8(float4 a, float4 b) {
  bf16x8 r;
  r[0] = (__bf16)a.x; r[1] = (__bf16)a.y; r[2] = (__bf16)a.z; r[3] = (__bf16)a.w;
  r[4] = (__bf16)b.x; r[5] = (__bf16)b.y; r[6] = (__bf16)b.z; r[7] = (__bf16)b.w;
  return r;
}
__device__ __forceinline__ f32x4 mfma(bf16x8 a, bf16x8 b, f32x4 c) {
  return __builtin_amdgcn_mfma_f32_16x16x32_bf16(a, b, c, 0, 0, 0);
}
__device__ __forceinline__ void gl16(const void* g, void* l) {
  __builtin_amdgcn_global_load_lds(
      (const __attribute__((address_space(1))) void*)g,
      (__attribute__((address_space(3))) void*)l, 16, 0, 0);
}
#define SCHEDB() __builtin_amdgcn_sched_barrier(0)
#define BAR()    __builtin_amdgcn_s_barrier()
#define VMW(n)   asm volatile("s_waitcnt vmcnt(" #n ")" ::: "memory")
#define LGKM0()  asm volatile("s_waitcnt lgkmcnt(0)" ::: "memory")
#define PSYNC()  do { SCHEDB(); \
    asm volatile("s_waitcnt vmcnt(0) lgkmcnt(0)" ::: "memory"); \
    BAR(); SCHEDB(); } while (0)

// fp32 tile frag read (R5-verified pair): rows of 32 floats, 16B chunk ^= r&7
#define RD8(arr, o_, r_, kb_) cvt8(                                              \
    *(const float4*)&(arr)[(o_) + (r_) * 32 + ((((kb_)*2    ) ^ ((r_)&7)) << 2)], \
    *(const float4*)&(arr)[(o_) + (r_) * 32 + ((((kb_)*2 + 1) ^ ((r_)&7)) << 2)])
// bf16 tile frag read (R5-verified pair): rows of 32 u16, 16B chunk ^= (r>>1)&3
#define RDB(arr, o_, r_, kb_) __builtin_bit_cast(bf16x8,                         \
    *(const u16x8*)&(arr)[(o_) + (r_) * 32 + (((kb_) ^ (((r_)>>1)&3)) << 3)])

// ---------------------------------------------------------------------------
__global__ __launch_bounds__(256) void moe_cvtx(const float* __restrict__ x,
                                                u16* __restrict__ xb) {
  const int i = (blockIdx.x * 256 + threadIdx.x) * 8;
  const float4 f0 = *(const float4*)(x + i);
  const float4 f1 = *(const float4*)(x + i + 4);
  *(uint4*)(xb + i) = __builtin_bit_cast(uint4, cvt8(f0, f1));
}

// ---------------------------------------------------------------------------
// Dispatch: expert bucketing + 128-row tile table.
// meta: [0..8] offs, [14] ntiles128, [48+t] e128, [80+t] r0_128 (t<24).
// ---------------------------------------------------------------------------
__global__ void moe_dispatch(const int* __restrict__ idx,
                             int* __restrict__ meta, int* __restrict__ perm) {
  __shared__ int s_cnt[NE];
  __shared__ int s_off[NE + 1];
  __shared__ int s_cur[NE];
  const int tid = threadIdx.x;
  if (tid < NE) { s_cnt[tid] = 0; s_cur[tid] = 0; }
  __syncthreads();
  for (int n = tid; n < NTOT; n += 256) atomicAdd(&s_cnt[idx[n]], 1);
  __syncthreads();
  if (tid == 0) {
    int a = 0;
    for (int e = 0; e < NE; ++e) { s_off[e] = a; a += s_cnt[e]; }
    s_off[NE] = a;
  }
  __syncthreads();
  for (int n = tid; n < NTOT; n += 256) {
    const int e = idx[n];
    perm[s_off[e] + atomicAdd(&s_cur[e], 1)] = n;
  }
  if (tid == 0) {
    int t2 = 0;
    for (int e = 0; e < NE; ++e) {
      for (int r0 = s_off[e]; r0 < s_off[e + 1]; r0 += 128) {
        meta[48 + t2] = e; meta[80 + t2] = r0; ++t2;
      }
    }
    meta[14] = t2;
  }
  if (tid < NE + 1) meta[tid] = s_off[tid];
}

// ---------------------------------------------------------------------------
// Stage 1 (R17-exact): h = silu(X Wg^T) * (X Wu^T). BM=128, BN=64(G)+64(U),
// BK=32. grid = MAXT2*32. 256 thr = 4 waves (2M x 2N); wave = 64M x 32N of
// both. Ring-2 LDS 48KB -> 3 blocks/CU. 6 gl16/thread/step, drain per step.
// ---------------------------------------------------------------------------
__global__ __launch_bounds__(256, 3) void moe_stage1(
    const u16* __restrict__ xb, const int* __restrict__ perm,
    const int* __restrict__ meta, const float* __restrict__ wg,
    const float* __restrict__ wu, u16* __restrict__ hbuf) {
  const int t = blockIdx.x >> 5;
  if (t >= meta[14]) return;
  const int nt = blockIdx.x & 31;  // H cols nt*64
  const int e = meta[48 + t];
  const int r0 = meta[80 + t];
  const int rows = min(128, meta[e + 1] - r0);

  __shared__ __align__(16) u16   sX[2 * 128 * 32];  // 8KB/buf
  __shared__ __align__(16) float sG[2 * 64 * 32];   // 8KB/buf
  __shared__ __align__(16) float sU[2 * 64 * 32];   // 8KB/buf

  const int tid = threadIdx.x;
  const int lane = tid & 63;
  const int wv = tid >> 6;
  const int wm = (wv >> 1) * 64;  // 0,64
  const int wn = (wv & 1) * 32;   // 0,32

  const u16* gpX[2];
  int lbX[2];
#pragma unroll
  for (int j = 0; j < 2; ++j) {
    const int r = wv * 32 + j * 16 + (lane >> 2);
    const int tok = perm[r0 + min(r, rows - 1)] >> 1;  // TOPK=2
    gpX[j] = xb + (size_t)tok * DDIM + (((lane & 3) ^ ((r >> 1) & 3)) << 3);
    lbX[j] = (wv * 32 + j * 16) * 32;
  }
  const float* gpG[2];
  const float* gpU[2];
  int lbW[2];
#pragma unroll
  for (int j = 0; j < 2; ++j) {
    const int r = wv * 16 + j * 8 + (lane >> 3);
    const size_t row = (size_t)e * HDIM + nt * 64 + r;
    gpG[j] = wg + row * DDIM + (((lane & 7) ^ (r & 7)) << 2);
    gpU[j] = wu + row * DDIM + (((lane & 7) ^ (r & 7)) << 2);
    lbW[j] = (wv * 16 + j * 8) * 32;
  }

  f32x4 aG[4][2] = {};
  f32x4 aU[4][2] = {};

#define S1_STAGE(b, kt) do {                                      \
    const int ko_ = (kt) * 32;                                    \
    gl16(gpX[0] + ko_, &sX[(b) * 4096 + lbX[0]]);                 \
    gl16(gpX[1] + ko_, &sX[(b) * 4096 + lbX[1]]);                 \
    gl16(gpG[0] + ko_, &sG[(b) * 2048 + lbW[0]]);                 \
    gl16(gpG[1] + ko_, &sG[(b) * 2048 + lbW[1]]);                 \
    gl16(gpU[0] + ko_, &sU[(b) * 2048 + lbW[0]]);                 \
    gl16(gpU[1] + ko_, &sU[(b) * 2048 + lbW[1]]);                 \
  } while (0)

#define S1_COMPUTE(b) do {                                        \
    const int fr_ = lane & 15, kb_ = lane >> 4;                   \
    bf16x8 a0 = RDB(sX, (b) * 4096, wm + fr_, kb_);               \
    bf16x8 a1 = RDB(sX, (b) * 4096, wm + 16 + fr_, kb_);          \
    bf16x8 a2 = RDB(sX, (b) * 4096, wm + 32 + fr_, kb_);          \
    bf16x8 a3 = RDB(sX, (b) * 4096, wm + 48 + fr_, kb_);          \
    bf16x8 g0 = RD8(sG, (b) * 2048, wn + fr_, kb_);               \
    bf16x8 g1 = RD8(sG, (b) * 2048, wn + 16 + fr_, kb_);          \
    bf16x8 u0 = RD8(sU, (b) * 2048, wn + fr_, kb_);               \
    bf16x8 u1 = RD8(sU, (b) * 2048, wn + 16 + fr_, kb_);          \
    aG[0][0] = mfma(a0, g0, aG[0][0]);                            \
    aG[1][0] = mfma(a1, g0, aG[1][0]);                            \
    aG[2][0] = mfma(a2, g0, aG[2][0]);                            \
    aG[3][0] = mfma(a3, g0, aG[3][0]);                            \
    aG[0][1] = mfma(a0, g1, aG[0][1]);                            \
    aG[1][1] = mfma(a1, g1, aG[1][1]);                            \
    aG[2][1] = mfma(a2, g1, aG[2][1]);                            \
    aG[3][1] = mfma(a3, g1, aG[3][1]);                            \
    aU[0][0] = mfma(a0, u0, aU[0][0]);                            \
    aU[1][0] = mfma(a1, u0, aU[1][0]);                            \
    aU[2][0] = mfma(a2, u0, aU[2][0]);                            \
    aU[3][0] = mfma(a3, u0, aU[3][0]);                            \
    aU[0][1] = mfma(a0, u1, aU[0][1]);                            \
    aU[1][1] = mfma(a1, u1, aU[1][1]);                            \
    aU[2][1] = mfma(a2, u1, aU[2][1]);                            \
    aU[3][1] = mfma(a3, u1, aU[3][1]);                            \
  } while (0)

  S1_STAGE(0, 0);
  PSYNC();
#pragma unroll 1
  for (int kt = 0; kt < 24; ++kt) {
    const int cb = kt & 1;
    if (kt + 1 < 24) S1_STAGE(cb ^ 1, kt + 1);
    SCHEDB();
    S1_COMPUTE(cb);
    PSYNC();
  }

  // epilogue: C/D layout col=lane&15, row=(lane>>4)*4+reg
  const int crow = (lane >> 4) << 2;
  const int ccol = lane & 15;
#pragma unroll
  for (int mi = 0; mi < 4; ++mi) {
#pragma unroll
    for (int ri = 0; ri < 4; ++ri) {
      const int lm = wm + mi * 16 + crow + ri;
      if (lm < rows) {
        u16* hb = hbuf + (size_t)(r0 + lm) * HDIM + nt * 64 + wn;
#pragma unroll
        for (int nj = 0; nj < 2; ++nj) {
          const float gv = aG[mi][nj][ri];
          const float uv = aU[mi][nj][ri];
          const float h = gv / (1.0f + __expf(-gv)) * uv;
          hb[nj * 16 + ccol] = f2bf(h);
        }
      }
    }
  }
}

// ---------------------------------------------------------------------------
// Stage 2: out += h Wd^T. BM=128, BN=64, BK=32, split-K=2.
// Ring-2 LDS 32KB -> 5 blocks/CU. Counted-1-deep: stage(l+1) flies during
// compute(l); 2 barriers/step (read-done, write-visible).
// ---------------------------------------------------------------------------
__global__ __launch_bounds__(256, 5) void moe_stage2(
    const u16* __restrict__ hbuf, const int* __restrict__ perm,
    const int* __restrict__ meta, const float* __restrict__ wd,
    float* __restrict__ out) {
  const int t = blockIdx.x / 24;
  if (t >= meta[14]) return;
  const int rem = blockIdx.x - t * 24;
  const int ks = rem / 12;
  const int nt = rem - ks * 12;
  const int e = meta[48 + t];
  const int r0 = meta[80 + t];
  const int rows = min(128, meta[e + 1] - r0);

  __shared__ __align__(16) u16   sA[2 * 128 * 32];  // 8KB/buf
  __shared__ __align__(16) float sB[2 * 64 * 32];   // 8KB/buf

  const int tid = threadIdx.x;
  const int lane = tid & 63;
  const int wv = tid >> 6;
  const int wm = (wv >> 1) * 64;
  const int wn = (wv & 1) * 32;

  const u16* gpA[2];
  int lbA[2];
#pragma unroll
  for (int j = 0; j < 2; ++j) {
    const int r = wv * 32 + j * 16 + (lane >> 2);
    gpA[j] = hbuf + (size_t)(r0 + min(r, rows - 1)) * HDIM + ks * 1024 +
             (((lane & 3) ^ ((r >> 1) & 3)) << 3);
    lbA[j] = (wv * 32 + j * 16) * 32;
  }
  const float* gpB[2];
  int lbB[2];
#pragma unroll
  for (int j = 0; j < 2; ++j) {
    const int r = wv * 16 + j * 8 + (lane >> 3);
    gpB[j] = wd + ((size_t)e * DDIM + nt * 64 + r) * HDIM + ks * 1024 +
             (((lane & 7) ^ (r & 7)) << 2);
    lbB[j] = (wv * 16 + j * 8) * 32;
  }

  f32x4 acc[4][2] = {};

#define S2_STAGE(slot, kp) do {                                   \
    const int su_ = (slot) * 4096, sf_ = (slot) * 2048;           \
    const int ko_ = (kp) * 32;                                    \
    gl16(gpA[0] + ko_, &sA[su_ + lbA[0]]);                        \
    gl16(gpA[1] + ko_, &sA[su_ + lbA[1]]);                        \
    gl16(gpB[0] + ko_, &sB[sf_ + lbB[0]]);                        \
    gl16(gpB[1] + ko_, &sB[sf_ + lbB[1]]);                        \
  } while (0)

#define S2_COMPUTE(slot) do {                                     \
    const int su_ = (slot) * 4096, sf_ = (slot) * 2048;           \
    const int fr_ = lane & 15, kb_ = lane >> 4;                   \
    bf16x8 a0 = RDB(sA, su_, wm + fr_, kb_);                      \
    bf16x8 a1 = RDB(sA, su_, wm + 16 + fr_, kb_);                 \
    bf16x8 a2 = RDB(sA, su_, wm + 32 + fr_, kb_);                 \
    bf16x8 a3 = RDB(sA, su_, wm + 48 + fr_, kb_);                 \
    bf16x8 b0 = RD8(sB, sf_, wn + fr_, kb_);                      \
    bf16x8 b1 = RD8(sB, sf_, wn + 16 + fr_, kb_);                 \
    acc[0][0] = mfma(a0, b0, acc[0][0]);                          \
    acc[1][0] = mfma(a1, b0, acc[1][0]);                          \
    acc[2][0] = mfma(a2, b0, acc[2][0]);                          \
    acc[3][0] = mfma(a3, b0, acc[3][0]);                          \
    acc[0][1] = mfma(a0, b1, acc[0][1]);                          \
    acc[1][1] = mfma(a1, b1, acc[1][1]);                          \
    acc[2][1] = mfma(a2, b1, acc[2][1]);                          \
    acc[3][1] = mfma(a3, b1, acc[3][1]);                          \
  } while (0)

  // prologue: 2 tiles in flight; buf0 complete before first compute
  S2_STAGE(0, 0);
  S2_STAGE(1, 1);
  VMW(4);   // buf0 done (buf1's 4 outstanding)
  BAR();

#pragma unroll 1
  for (int l = 0; l < 32; ++l) {
    const int cur = l & 1;
    S2_COMPUTE(cur);
    SCHEDB();
    LGKM0();           // my reads of buf cur are done
    BAR();             // everyone's reads of buf cur are done
    if (l + 2 < 32) {
      S2_STAGE(cur, l + 2);  // overwrite freed buf; (l+1) still in flight
      VMW(4);                // (l+1) complete; (l+2)'s 4 outstanding
    } else if (l + 1 < 32) {
      VMW(0);                // drain (l+1) for the final compute
    }
    BAR();
  }

  const int crow = (lane >> 4) << 2;
  const int ccol = lane & 15;
#pragma unroll
  for (int mi = 0; mi < 4; ++mi) {
#pragma unroll
    for (int ri = 0; ri < 4; ++ri) {
      const int lm = wm + mi * 16 + crow + ri;
      if (lm < rows) {
        const int tok = perm[r0 + lm];
        float* orow = out + (size_t)tok * DDIM + nt * 64 + wn;
#pragma unroll
        for (int nj = 0; nj < 2; ++nj) {
          atomicAdd(&orow[nj * 16 + ccol], acc[mi][nj][ri]);
        }
      }
    }
  }
}

// ---------------------------------------------------------------------------
extern "C" void kernel_launch(void* const* d_in, const int* in_sizes, int n_in,
                              void* d_out, int out_size, void* d_ws, size_t ws_size,
                              hipStream_t stream) {
  const float* x  = (const float*)d_in[0];
  const int* idx  = (const int*)d_in[1];
  const float* wg = (const float*)d_in[2];
  const float* wu = (const float*)d_in[3];
  const float* wd = (const float*)d_in[4];
  float* out = (float*)d_out;

  int* iws = (int*)d_ws;
  int* meta = iws;        // layout in moe_dispatch comment
  int* perm = iws + 128;  // 2048 ints
  u16* xbuf = (u16*)((char*)d_ws + 16384);              // 1024x768 bf16
  u16* hbuf = (u16*)((char*)d_ws + 16384 + (1 << 21));  // 2048x2048 bf16

  hipMemsetAsync(d_out, 0, (size_t)out_size * sizeof(float), stream);
  moe_cvtx<<<NTOK * DDIM / 2048, 256, 0, stream>>>(x, xbuf);
  moe_dispatch<<<1, 256, 0, stream>>>(idx, meta, perm);
  moe_stage1<<<MAXT2 * 32, 256, 0, stream>>>(xbuf, perm, meta, wg, wu, hbuf);
  moe_stage2<<<MAXT2 * 24, 256, 0, stream>>>(hbuf, perm, meta, wd, out);
}